// Round 2
// baseline (489.888 us; speedup 1.0000x reference)
//
#include <hip/hip_runtime.h>
#include <hip/hip_cooperative_groups.h>
#include <cstddef>

namespace cg = cooperative_groups;

#define H   256
#define L   2048
#define B   32
#define V   50257
#define H2  512
#define H4  1024
#define CH  64                        // flash chunk rows
#define NCH (L/CH)                    // 32 chunks per batch

// output flat offsets (floats)
#define LP_OFF 0
#define HN_OFF (B*V)                 // 1608224
#define CN_OFF (HN_OFF + B*H)        // 1616416
#define AW_OFF (CN_OFF + B*H)        // 1624608

// workspace layout (floats)
#define WS_XL    0                    // 32*512: [h_new | attn_applied]
#define WS_S     (WS_XL + B*H2)       // 32*2048 raw scores
#define WS_AV    (WS_S + B*L)         // 1024*256 chunk partial vectors
#define WS_AM    (WS_AV + B*NCH*H)    // 1024 chunk max
#define WS_AZ    (WS_AM + B*NCH)      // 1024 chunk sumexp
#define WS_PM    (WS_AZ + B*NCH)      // 32*800 lsm per-tile max
#define WS_PZ    (WS_PM + 32*800)     // 32*800 lsm per-tile sumexp

#define NT_LOG 786                    // ceil(V/64) 64-row logit tiles
#define NBLK   512                    // cooperative grid size (2 blocks/CU)

typedef __attribute__((ext_vector_type(8))) short bf16x8;
typedef __attribute__((ext_vector_type(4))) float f32x4;

__device__ inline unsigned short f2bf(float f) {
    unsigned u = __builtin_bit_cast(unsigned, f);
    u += 0x7FFFu + ((u >> 16) & 1u);          // RNE to bf16
    return (unsigned short)(u >> 16);
}

// Single cooperative kernel; phases [p_lo, p_hi] with grid.sync() between.
// Phase 0: flash attention (2 chunk-units per block)
// Phase 1: comb + gates + lstm (unit = (b, 16-row slice))
// Phase 2: logits MFMA, 64-row tiles with depth-2 W_out prefetch
// Phase 3: log-softmax finalize (unit = (b, 4096-logit chunk))
__global__ __launch_bounds__(256, 2) void k_mega(
    int p_lo, int p_hi,
    const int*   __restrict__ tokens, const float* __restrict__ emb,
    const float* __restrict__ hidden, const float* __restrict__ cell,
    const float* __restrict__ enc,    const float* __restrict__ W_attn,
    const float* __restrict__ v,      const float* __restrict__ W_ih,
    const float* __restrict__ b_ih,   const float* __restrict__ W_hh,
    const float* __restrict__ b_hh,   const float* __restrict__ W_out,
    const float* __restrict__ b_out,  float* __restrict__ ws,
    float* __restrict__ out)
{
    __shared__ __align__(16) float smf[8576];   // 34,304 B, aliased per phase
    cg::grid_group grid = cg::this_grid();
    int blk = blockIdx.x, t = threadIdx.x;
    int wave = t >> 6, lane = t & 63;

    // ================= phase 0: flash attention =================
    if (p_lo <= 0 && 0 <= p_hi) {
        float* v_s   = smf;           // 256
        float* w_s   = smf + 256;     // 256
        float* s_lds = smf + 512;     // 64
        float* p_lds = smf + 576;     // 64
        float* red   = smf + 640;     // 64
        float* vec   = smf + 704;     // 4*256
        int g = lane >> 4, u = lane & 15;

        v_s[t] = v[t];
        __syncthreads();
        {
            const float* base = W_attn + H + t;
            float wa = 0.f, wb = 0.f;
            #pragma unroll 8
            for (int k = 0; k < H; k += 2) {
                wa += v_s[k]     * base[(size_t)k * H2];
                wb += v_s[k + 1] * base[(size_t)(k + 1) * H2];
            }
            w_s[t] = wa + wb;
        }
        __syncthreads();
        const float4* w4s = (const float4*)w_s;
        float4 w0 = w4s[u], w1 = w4s[16 + u], w2 = w4s[32 + u], w3 = w4s[48 + u];

        for (int pass = 0; pass < 2; pass++) {
            int bid = blk + pass * NBLK;          // 0..1023
            int b = bid >> 5, chunk = bid & (NCH - 1);
            size_t rowbase = (size_t)b * L + chunk * CH;

            #pragma unroll
            for (int ir = 0; ir < 4; ir++) {
                int rl = wave * 16 + ir * 4 + g;
                const float4* e4 = (const float4*)(enc + (rowbase + rl) * H);
                float4 a0 = e4[u], a1 = e4[16 + u], a2 = e4[32 + u], a3 = e4[48 + u];
                float p = a0.x * w0.x + a0.y * w0.y + a0.z * w0.z + a0.w * w0.w
                        + a1.x * w1.x + a1.y * w1.y + a1.z * w1.z + a1.w * w1.w
                        + a2.x * w2.x + a2.y * w2.y + a2.z * w2.z + a2.w * w2.w
                        + a3.x * w3.x + a3.y * w3.y + a3.z * w3.z + a3.w * w3.w;
                p += __shfl_down(p, 8); p += __shfl_down(p, 4);
                p += __shfl_down(p, 2); p += __shfl_down(p, 1);
                if (u == 0) s_lds[rl] = p;
            }
            __syncthreads();

            if (t < CH) red[t] = s_lds[t];
            __syncthreads();
            for (int off = 32; off; off >>= 1) { if (t < off) red[t] = fmaxf(red[t], red[t + off]); __syncthreads(); }
            float m = red[0];
            __syncthreads();
            if (t < CH) {
                float e = __expf(s_lds[t] - m);
                p_lds[t] = e; red[t] = e;
                ws[WS_S + rowbase + t] = s_lds[t];
            }
            __syncthreads();
            for (int off = 32; off; off >>= 1) { if (t < off) red[t] += red[t + off]; __syncthreads(); }

            float4 acc = make_float4(0.f, 0.f, 0.f, 0.f);
            const float4* ebase = (const float4*)(enc + (rowbase + wave * 16) * H);
            #pragma unroll 4
            for (int i = 0; i < 16; i++) {
                float p = p_lds[wave * 16 + i];
                float4 a = ebase[i * 64 + lane];
                acc.x += p * a.x; acc.y += p * a.y; acc.z += p * a.z; acc.w += p * a.w;
            }
            *(float4*)&vec[wave * 256 + lane * 4] = acc;
            __syncthreads();
            ws[WS_AV + (size_t)bid * 256 + t] = vec[t] + vec[256 + t] + vec[512 + t] + vec[768 + t];
            if (t == 0) { ws[WS_AM + bid] = m; ws[WS_AZ + bid] = red[0]; }
            __syncthreads();                      // protect smem for next pass
        }
    }
    if (p_lo <= 0 && 1 <= p_hi) grid.sync();

    // ================= phase 1: comb + gates + lstm =================
    if (p_lo <= 1 && 1 <= p_hi) {
        int b = blk >> 4, s = blk & 15;
        float* mc = smf;              // 32
        float* zc = smf + 32;         // 32
        float* xs = smf + 64;         // 512
        float* hs = smf + 576;        // 256
        float* gl = smf + 832;        // 64

        if (t < NCH) { mc[t] = ws[WS_AM + b * NCH + t]; zc[t] = ws[WS_AZ + b * NCH + t]; }
        hs[t] = hidden[(size_t)b * H + t];
        xs[t] = emb[(size_t)tokens[b] * H + t];
        __syncthreads();

        float M = -1e30f;
        #pragma unroll
        for (int c = 0; c < NCH; c++) M = fmaxf(M, mc[c]);
        float Z = 0.f;
        #pragma unroll
        for (int c = 0; c < NCH; c++) Z += zc[c] * __expf(mc[c] - M);
        float inv = 1.f / Z;
        float acc = 0.f;
        #pragma unroll 8
        for (int c = 0; c < NCH; c++) acc += __expf(mc[c] - M) * ws[WS_AV + (size_t)(b * NCH + c) * H + t];
        acc *= inv;
        xs[H + t] = acc;
        if (s == 0) {
            ws[WS_XL + b * H2 + H + t] = acc;
            #pragma unroll
            for (int j = 0; j < 8; j++) {
                int l = t + 256 * j;
                out[AW_OFF + (size_t)b * L + l] = __expf(ws[WS_S + (size_t)b * L + l] - M) * inv;
            }
        }
        __syncthreads();

        int ts = s * 16;
        const float4* xs4 = (const float4*)xs;
        const float4* hs4 = (const float4*)hs;
        float4 x0 = xs4[lane * 2], x1 = xs4[lane * 2 + 1];
        float4 xh = hs4[lane];
        for (int it = 0; it < 16; it++) {
            int j = (wave << 8) + ts + it;                 // gate row in [0,1024)
            const float4* wi = (const float4*)(W_ih + (size_t)j * H2);
            float4 a0 = wi[lane * 2], a1 = wi[lane * 2 + 1];
            const float4* wh = (const float4*)(W_hh + (size_t)j * H);
            float4 a2 = wh[lane];
            float p = a0.x * x0.x + a0.y * x0.y + a0.z * x0.z + a0.w * x0.w
                    + a1.x * x1.x + a1.y * x1.y + a1.z * x1.z + a1.w * x1.w
                    + a2.x * xh.x + a2.y * xh.y + a2.z * xh.z + a2.w * xh.w;
            #pragma unroll
            for (int off = 32; off; off >>= 1) p += __shfl_down(p, off);
            if (lane == 0) gl[wave * 16 + it] = p + b_ih[j] + b_hh[j];
        }
        __syncthreads();

        if (t < 16) {
            int tt = ts + t;
            float ig = gl[t], fg = gl[16 + t], gg = gl[32 + t], og = gl[48 + t];
            float c = cell[(size_t)b * H + tt];
            float si = 1.f / (1.f + expf(-ig));
            float sf = 1.f / (1.f + expf(-fg));
            float so = 1.f / (1.f + expf(-og));
            float cn = sf * c + si * tanhf(gg);
            float hn = so * tanhf(cn);
            out[HN_OFF + b * H + tt] = hn;
            out[CN_OFF + b * H + tt] = cn;
            ws[WS_XL + b * H2 + tt] = hn;
        }
    }
    if (p_lo <= 1 && 2 <= p_hi) grid.sync();

    // ================= phase 2: logits MFMA =================
    if (p_lo <= 2 && 2 <= p_hi) {
        unsigned short* Xl = (unsigned short*)smf;     // 32*520 shorts = 33,280 B
        float* red2 = smf + 8320;                      // 256 floats, beyond Xl
        const float4* xl4 = (const float4*)(ws + WS_XL);
        #pragma unroll
        for (int it = 0; it < 16; it++) {
            int fi = t + 256 * it;                     // float4 index over 32x128
            int bb = fi >> 7, kq = fi & 127;
            float4 xv = xl4[bb * 128 + kq];
            unsigned p0 = (unsigned)f2bf(xv.x) | ((unsigned)f2bf(xv.y) << 16);
            unsigned p1 = (unsigned)f2bf(xv.z) | ((unsigned)f2bf(xv.w) << 16);
            unsigned* dst = (unsigned*)&Xl[bb * 520 + kq * 4];
            dst[0] = p0; dst[1] = p1;
        }
        __syncthreads();

        int quad = lane >> 4, m = lane & 15;
        for (int tile = blk; tile < NT_LOG; tile += NBLK) {
            int rbase = tile * 64 + wave * 16;
            int r0 = rbase + m;
            int rc = r0 < V ? r0 : V - 1;
            const float* wp = W_out + (size_t)rc * H2 + quad * 8;
            f32x4 acc0 = {0.f, 0.f, 0.f, 0.f}, acc1 = {0.f, 0.f, 0.f, 0.f};

            float4 lo = *(const float4*)(wp);
            float4 hi = *(const float4*)(wp + 4);
            #pragma unroll
            for (int kp = 0; kp < 16; kp++) {
                int k0 = kp * 32;
                float4 nlo, nhi;
                if (kp < 15) {                          // depth-2 prefetch
                    nlo = *(const float4*)(wp + k0 + 32);
                    nhi = *(const float4*)(wp + k0 + 36);
                }
                bf16x8 a;
                a[0]=(short)f2bf(lo.x); a[1]=(short)f2bf(lo.y); a[2]=(short)f2bf(lo.z); a[3]=(short)f2bf(lo.w);
                a[4]=(short)f2bf(hi.x); a[5]=(short)f2bf(hi.y); a[6]=(short)f2bf(hi.z); a[7]=(short)f2bf(hi.w);
                bf16x8 b0 = *(bf16x8*)&Xl[(size_t)m * 520 + k0 + quad * 8];
                bf16x8 b1 = *(bf16x8*)&Xl[(size_t)(16 + m) * 520 + k0 + quad * 8];
                acc0 = __builtin_amdgcn_mfma_f32_16x16x32_bf16(a, b0, acc0, 0, 0, 0);
                acc1 = __builtin_amdgcn_mfma_f32_16x16x32_bf16(a, b1, acc1, 0, 0, 0);
                lo = nlo; hi = nhi;
            }

            float val[2][4];
            #pragma unroll
            for (int i = 0; i < 4; i++) {
                int rr = rbase + quad * 4 + i;
                float bo = (rr < V) ? b_out[rr] : 0.f;
                float v0 = acc0[i] + bo, v1 = acc1[i] + bo;
                if (rr < V) {
                    out[(size_t)m * V + rr]        = v0;
                    out[(size_t)(16 + m) * V + rr] = v1;
                    val[0][i] = v0; val[1][i] = v1;
                } else { val[0][i] = -1e30f; val[1][i] = -1e30f; }
            }
            float pm[2], pz[2];
            #pragma unroll
            for (int nt = 0; nt < 2; nt++) {
                float mx = -1e30f;
                #pragma unroll
                for (int i = 0; i < 4; i++) mx = fmaxf(mx, val[nt][i]);
                float sm = 0.f;
                #pragma unroll
                for (int i = 0; i < 4; i++) sm += __expf(val[nt][i] - mx);
                pm[nt] = mx; pz[nt] = sm;
            }
            #pragma unroll
            for (int off = 16; off <= 32; off <<= 1) {
                #pragma unroll
                for (int nt = 0; nt < 2; nt++) {
                    float om = __shfl_xor(pm[nt], off);
                    float oz = __shfl_xor(pz[nt], off);
                    float nm = fmaxf(pm[nt], om);
                    pz[nt] = pz[nt] * __expf(pm[nt] - nm) + oz * __expf(om - nm);
                    pm[nt] = nm;
                }
            }
            __syncthreads();                            // red2 reuse across tiles
            if (quad == 0) {
                #pragma unroll
                for (int nt = 0; nt < 2; nt++) {
                    red2[wave * 32 + nt * 16 + m]       = pm[nt];
                    red2[128 + wave * 32 + nt * 16 + m] = pz[nt];
                }
            }
            __syncthreads();
            if (t < 32) {
                float mf = -1e30f;
                #pragma unroll
                for (int w = 0; w < 4; w++) mf = fmaxf(mf, red2[w * 32 + t]);
                float z = 0.f;
                #pragma unroll
                for (int w = 0; w < 4; w++) z += red2[128 + w * 32 + t] * __expf(red2[w * 32 + t] - mf);
                ws[WS_PM + t * 800 + tile] = mf;
                ws[WS_PZ + t * 800 + tile] = z;
            }
        }
    }
    if (p_lo <= 2 && 3 <= p_hi) grid.sync();

    // ================= phase 3: log-softmax finalize =================
    if (p_lo <= 3 && 3 <= p_hi) {
        if (blk < 416) {                               // 32 b x 13 chunks of 4096
            int b = blk / 13, ch = blk - b * 13;
            float* rm = smf;
            float* rz = smf + 256;
            float m = -1e30f, z = 0.f;
            for (int i = t; i < NT_LOG; i += 256) {
                float mi = ws[WS_PM + b * 800 + i];
                float zi = ws[WS_PZ + b * 800 + i];
                float nm = fmaxf(m, mi);
                z = z * __expf(m - nm) + zi * __expf(mi - nm);
                m = nm;
            }
            rm[t] = m; rz[t] = z; __syncthreads();
            for (int off = 128; off; off >>= 1) {
                if (t < off) {
                    float m2 = rm[t + off], z2 = rz[t + off];
                    float nm = fmaxf(rm[t], m2);
                    rz[t] = rz[t] * __expf(rm[t] - nm) + z2 * __expf(m2 - nm);
                    rm[t] = nm;
                }
                __syncthreads();
            }
            float MM = rm[0], LZ = logf(rz[0]);
            int rb = ch * 4096 + t;
            #pragma unroll
            for (int j = 0; j < 16; j++) {
                int r = rb + 256 * j;
                if (r < V) {
                    size_t i = (size_t)b * V + r;
                    out[i] = out[i] - MM - LZ;
                }
            }
        }
    }
}

extern "C" void kernel_launch(void* const* d_in, const int* in_sizes, int n_in,
                              void* d_out, int out_size, void* d_ws, size_t ws_size,
                              hipStream_t stream) {
    const int*   tokens = (const int*)d_in[0];
    const float* hidden = (const float*)d_in[1];
    const float* cell   = (const float*)d_in[2];
    const float* enc    = (const float*)d_in[3];
    const float* emb    = (const float*)d_in[4];
    const float* W_attn = (const float*)d_in[5];
    const float* v      = (const float*)d_in[7];
    const float* W_ih   = (const float*)d_in[8];
    const float* b_ih   = (const float*)d_in[9];
    const float* W_hh   = (const float*)d_in[10];
    const float* b_hh   = (const float*)d_in[11];
    const float* W_out  = (const float*)d_in[12];
    const float* b_out  = (const float*)d_in[13];
    float* out = (float*)d_out;
    float* ws  = (float*)d_ws;

    int p_lo = 0, p_hi = 3;
    void* args[] = { &p_lo, &p_hi, &tokens, &emb, &hidden, &cell, &enc, &W_attn,
                     &v, &W_ih, &b_ih, &W_hh, &b_hh, &W_out, &b_out, &ws, &out };
    hipError_t e = hipLaunchCooperativeKernel((const void*)k_mega, dim3(NBLK), dim3(256),
                                              args, 0, stream);
    if (e != hipSuccess) {
        // fallback: run phases as 4 ordinary dependent launches (no grid.sync taken)
        for (int p = 0; p < 4; p++) {
            k_mega<<<NBLK, 256, 0, stream>>>(p, p, tokens, emb, hidden, cell, enc, W_attn,
                                             v, W_ih, b_ih, W_hh, b_hh, W_out, b_out, ws, out);
        }
    }
}

// Round 3
// 302.965 us; speedup vs baseline: 1.6170x; 1.6170x over previous
//
#include <hip/hip_runtime.h>
#include <cstddef>

#define H   256
#define L   2048
#define B   32
#define V   50257
#define H2  512
#define H4  1024
#define CH  64                        // flash chunk rows
#define NCH (L/CH)                    // 32 chunks per batch

// output flat offsets (floats)
#define LP_OFF 0
#define HN_OFF (B*V)                 // 1608224
#define CN_OFF (HN_OFF + B*H)        // 1616416
#define AW_OFF (CN_OFF + B*H)        // 1624608

// workspace layout (floats)
#define WS_XL    0                    // 32*512: [h_new | attn_applied]
#define WS_S     (WS_XL + B*H2)       // 32*2048 raw scores
#define WS_AV    (WS_S + B*L)         // 1024*256 chunk partial vectors
#define WS_AM    (WS_AV + B*NCH*H)    // 1024 chunk max
#define WS_AZ    (WS_AM + B*NCH)      // 1024 chunk sumexp
#define WS_PM    (WS_AZ + B*NCH)      // 32*800 lsm per-tile max
#define WS_PZ    (WS_PM + 32*800)     // 32*800 lsm per-tile sumexp

#define NT_LOG 786                    // ceil(V/64) 64-row logit tiles

typedef __attribute__((ext_vector_type(8))) short bf16x8;
typedef __attribute__((ext_vector_type(4))) float f32x4;

__device__ inline unsigned short f2bf(float f) {
    unsigned u = __builtin_bit_cast(unsigned, f);
    u += 0x7FFFu + ((u >> 16) & 1u);          // RNE to bf16
    return (unsigned short)(u >> 16);
}

// ---------------------------------------------------------------- flash attention:
// block = (b, chunk of 64 l).  Computes w = v^T We in-block (W_attn L2-hot),
// then scores with k-split-16, chunk softmax partial, weighted vector partial.
__global__ __launch_bounds__(256) void k_attn(const float* __restrict__ W_attn,
                                              const float* __restrict__ v,
                                              const float* __restrict__ enc,
                                              float* __restrict__ ws) {
    int bid = blockIdx.x;             // b*NCH + chunk
    int b = bid >> 5, chunk = bid & (NCH - 1);
    int t = threadIdx.x;
    int wave = t >> 6, lane = t & 63;
    int g = lane >> 4, u = lane & 15;
    __shared__ float v_s[H];
    __shared__ float w_s[H];
    __shared__ float s_lds[CH];
    __shared__ float p_lds[CH];
    __shared__ float red[CH];
    __shared__ float vec_lds[4][256];

    // w[t] = sum_k v[k] * W_attn[k, H+t]
    v_s[t] = v[t];
    __syncthreads();
    {
        const float* base = W_attn + H + t;
        float wa = 0.f, wb = 0.f;
        #pragma unroll 8
        for (int k = 0; k < H; k += 2) {
            wa += v_s[k]     * base[(size_t)k * H2];
            wb += v_s[k + 1] * base[(size_t)(k + 1) * H2];
        }
        w_s[t] = wa + wb;
    }
    __syncthreads();

    size_t rowbase = (size_t)b * L + chunk * CH;
    const float4* w4s = (const float4*)w_s;
    float4 w0 = w4s[u], w1 = w4s[16 + u], w2 = w4s[32 + u], w3 = w4s[48 + u];

    // phase 1: scores.  wave handles rows [wave*16, wave*16+16), 4 at a time (one per g);
    // 16 lanes (u) split k, 4 independent float4 loads per lane per row.
    #pragma unroll
    for (int ir = 0; ir < 4; ir++) {
        int rl = wave * 16 + ir * 4 + g;
        const float4* e4 = (const float4*)(enc + (rowbase + rl) * H);
        float4 a0 = e4[u], a1 = e4[16 + u], a2 = e4[32 + u], a3 = e4[48 + u];
        float p = a0.x * w0.x + a0.y * w0.y + a0.z * w0.z + a0.w * w0.w
                + a1.x * w1.x + a1.y * w1.y + a1.z * w1.z + a1.w * w1.w
                + a2.x * w2.x + a2.y * w2.y + a2.z * w2.z + a2.w * w2.w
                + a3.x * w3.x + a3.y * w3.y + a3.z * w3.z + a3.w * w3.w;
        p += __shfl_down(p, 8); p += __shfl_down(p, 4);
        p += __shfl_down(p, 2); p += __shfl_down(p, 1);
        if (u == 0) s_lds[rl] = p;
    }
    __syncthreads();

    // chunk softmax partial over 64 rows
    if (t < CH) red[t] = s_lds[t];
    __syncthreads();
    for (int off = 32; off; off >>= 1) { if (t < off) red[t] = fmaxf(red[t], red[t + off]); __syncthreads(); }
    float m = red[0];
    __syncthreads();
    if (t < CH) {
        float e = __expf(s_lds[t] - m);
        p_lds[t] = e; red[t] = e;
        ws[WS_S + rowbase + t] = s_lds[t];
    }
    __syncthreads();
    for (int off = 32; off; off >>= 1) { if (t < off) red[t] += red[t + off]; __syncthreads(); }

    // phase 2: weighted vector partial; fully unrolled -> 16 float4 loads in flight
    float4 acc = make_float4(0.f, 0.f, 0.f, 0.f);
    const float4* ebase = (const float4*)(enc + (rowbase + wave * 16) * H);
    #pragma unroll
    for (int i = 0; i < 16; i++) {
        float p = p_lds[wave * 16 + i];
        float4 a = ebase[i * 64 + lane];
        acc.x += p * a.x; acc.y += p * a.y; acc.z += p * a.z; acc.w += p * a.w;
    }
    *(float4*)&vec_lds[wave][lane * 4] = acc;
    __syncthreads();
    ws[WS_AV + (size_t)bid * 256 + t] = vec_lds[0][t] + vec_lds[1][t] + vec_lds[2][t] + vec_lds[3][t];
    if (t == 0) { ws[WS_AM + bid] = m; ws[WS_AZ + bid] = red[0]; }
}

// ---------------------------------------------------------------- fused comb + gates + lstm:
// block = (b, s) with s = 16-row t-slice (16 slices per b -> 512 blocks).
__global__ __launch_bounds__(256) void k_fuse(const int* __restrict__ tokens,
                                              const float* __restrict__ emb,
                                              const float* __restrict__ hidden,
                                              const float* __restrict__ cell,
                                              const float* __restrict__ W_ih,
                                              const float* __restrict__ b_ih,
                                              const float* __restrict__ W_hh,
                                              const float* __restrict__ b_hh,
                                              float* __restrict__ ws,
                                              float* __restrict__ out) {
    int blk = blockIdx.x;
    int b = blk >> 4, s = blk & 15;
    int t = threadIdx.x;
    int wave = t >> 6, lane = t & 63;
    __shared__ float mc[NCH], zc[NCH];
    __shared__ float xs[H2];          // [embedded | attn_applied]
    __shared__ float hs[H];
    __shared__ float gl[64];          // gate results: [gate][16]

    if (t < NCH) { mc[t] = ws[WS_AM + b * NCH + t]; zc[t] = ws[WS_AZ + b * NCH + t]; }
    hs[t] = hidden[(size_t)b * H + t];
    xs[t] = emb[(size_t)tokens[b] * H + t];
    __syncthreads();

    // phase A: global softmax stats + weighted combine of chunk vectors
    float M = -1e30f;
    #pragma unroll
    for (int c = 0; c < NCH; c++) M = fmaxf(M, mc[c]);
    float Z = 0.f;
    #pragma unroll
    for (int c = 0; c < NCH; c++) Z += zc[c] * __expf(mc[c] - M);
    float inv = 1.f / Z;
    float acc = 0.f;
    #pragma unroll 8
    for (int c = 0; c < NCH; c++) acc += __expf(mc[c] - M) * ws[WS_AV + (size_t)(b * NCH + c) * H + t];
    acc *= inv;
    xs[H + t] = acc;
    if (s == 0) {
        ws[WS_XL + b * H2 + H + t] = acc;
        #pragma unroll
        for (int j = 0; j < 8; j++) {
            int l = t + 256 * j;
            out[AW_OFF + (size_t)b * L + l] = __expf(ws[WS_S + (size_t)b * L + l] - M) * inv;
        }
    }
    __syncthreads();

    // phase B: gates.  wave = gate index; 16 rows per wave; k split over 64 lanes.
    int ts = s * 16;
    const float4* xs4 = (const float4*)xs;
    const float4* hs4 = (const float4*)hs;
    float4 x0 = xs4[lane * 2], x1 = xs4[lane * 2 + 1];
    float4 xh = hs4[lane];
    for (int it = 0; it < 16; it++) {
        int j = (wave << 8) + ts + it;                     // gate row in [0,1024)
        const float4* wi = (const float4*)(W_ih + (size_t)j * H2);
        float4 a0 = wi[lane * 2], a1 = wi[lane * 2 + 1];
        const float4* wh = (const float4*)(W_hh + (size_t)j * H);
        float4 a2 = wh[lane];
        float p = a0.x * x0.x + a0.y * x0.y + a0.z * x0.z + a0.w * x0.w
                + a1.x * x1.x + a1.y * x1.y + a1.z * x1.z + a1.w * x1.w
                + a2.x * xh.x + a2.y * xh.y + a2.z * xh.z + a2.w * xh.w;
        #pragma unroll
        for (int off = 32; off; off >>= 1) p += __shfl_down(p, off);
        if (lane == 0) gl[wave * 16 + it] = p + b_ih[j] + b_hh[j];
    }
    __syncthreads();

    // phase C: LSTM pointwise for this block's 16 t's
    if (t < 16) {
        int tt = ts + t;
        float ig = gl[t], fg = gl[16 + t], gg = gl[32 + t], og = gl[48 + t];
        float c = cell[(size_t)b * H + tt];
        float si = 1.f / (1.f + expf(-ig));
        float sf = 1.f / (1.f + expf(-fg));
        float so = 1.f / (1.f + expf(-og));
        float cn = sf * c + si * tanhf(gg);
        float hn = so * tanhf(cn);
        out[HN_OFF + b * H + tt] = hn;
        out[CN_OFF + b * H + tt] = cn;
        ws[WS_XL + b * H2 + tt] = hn;
    }
}

// ---------------------------------------------------------------- logits (bf16 MFMA):
// 786 blocks x 64 rows.  wave = 16-row strip x 32 batches (2 n-tiles).
// Depth-3 rotating register prefetch of W_out (6 x float4 in flight per lane).
__global__ __launch_bounds__(256, 4) void k_logits(const float* __restrict__ W_out,
                                                   const float* __restrict__ b_out,
                                                   float* __restrict__ ws,
                                                   float* __restrict__ out) {
    __shared__ unsigned short Xl[32 * 520];   // 33,280 B
    __shared__ float red2[256];
    int t = threadIdx.x;
    const float4* xl4 = (const float4*)(ws + WS_XL);
    #pragma unroll
    for (int it = 0; it < 16; it++) {
        int fi = t + 256 * it;                // float4 index over 32x128
        int bb = fi >> 7, kq = fi & 127;
        float4 xv = xl4[bb * 128 + kq];
        unsigned p0 = (unsigned)f2bf(xv.x) | ((unsigned)f2bf(xv.y) << 16);
        unsigned p1 = (unsigned)f2bf(xv.z) | ((unsigned)f2bf(xv.w) << 16);
        unsigned* dst = (unsigned*)&Xl[bb * 520 + kq * 4];
        dst[0] = p0; dst[1] = p1;
    }
    __syncthreads();

    int wave = t >> 6, lane = t & 63, quad = lane >> 4, m = lane & 15;
    int rbase = blockIdx.x * 64 + wave * 16;
    int r0 = rbase + m;
    int rc = r0 < V ? r0 : V - 1;
    const float4* wq = (const float4*)(W_out + (size_t)rc * H2 + quad * 8);

    f32x4 acc0 = {0.f, 0.f, 0.f, 0.f}, acc1 = {0.f, 0.f, 0.f, 0.f};

    // depth-3 prefetch ring (kp, kp+1, kp+2 resident; kp+3 issued on rotate)
    float4 pl0 = wq[0],  ph0 = wq[1];
    float4 pl1 = wq[8],  ph1 = wq[9];
    float4 pl2 = wq[16], ph2 = wq[17];
    #pragma unroll
    for (int kp = 0; kp < 16; kp++) {
        int k0 = kp * 32;
        bf16x8 a;
        a[0]=(short)f2bf(pl0.x); a[1]=(short)f2bf(pl0.y); a[2]=(short)f2bf(pl0.z); a[3]=(short)f2bf(pl0.w);
        a[4]=(short)f2bf(ph0.x); a[5]=(short)f2bf(ph0.y); a[6]=(short)f2bf(ph0.z); a[7]=(short)f2bf(ph0.w);
        bf16x8 b0 = *(bf16x8*)&Xl[(size_t)m * 520 + k0 + quad * 8];
        bf16x8 b1 = *(bf16x8*)&Xl[(size_t)(16 + m) * 520 + k0 + quad * 8];
        acc0 = __builtin_amdgcn_mfma_f32_16x16x32_bf16(a, b0, acc0, 0, 0, 0);
        acc1 = __builtin_amdgcn_mfma_f32_16x16x32_bf16(a, b1, acc1, 0, 0, 0);
        pl0 = pl1; ph0 = ph1;
        pl1 = pl2; ph1 = ph2;
        if (kp < 13) { pl2 = wq[(kp + 3) * 8]; ph2 = wq[(kp + 3) * 8 + 1]; }
    }

    // epilogue: bias, store, per-wave softmax partials
    float val[2][4];
    #pragma unroll
    for (int i = 0; i < 4; i++) {
        int rr = rbase + quad * 4 + i;
        float bo = (rr < V) ? b_out[rr] : 0.f;
        float v0 = acc0[i] + bo, v1 = acc1[i] + bo;
        if (rr < V) {
            out[(size_t)m * V + rr]        = v0;
            out[(size_t)(16 + m) * V + rr] = v1;
            val[0][i] = v0; val[1][i] = v1;
        } else { val[0][i] = -1e30f; val[1][i] = -1e30f; }
    }
    float pm[2], pz[2];
    #pragma unroll
    for (int nt = 0; nt < 2; nt++) {
        float mx = -1e30f;
        #pragma unroll
        for (int i = 0; i < 4; i++) mx = fmaxf(mx, val[nt][i]);
        float sm = 0.f;
        #pragma unroll
        for (int i = 0; i < 4; i++) sm += __expf(val[nt][i] - mx);
        pm[nt] = mx; pz[nt] = sm;
    }
    #pragma unroll
    for (int off = 16; off <= 32; off <<= 1) {
        #pragma unroll
        for (int nt = 0; nt < 2; nt++) {
            float om = __shfl_xor(pm[nt], off);
            float oz = __shfl_xor(pz[nt], off);
            float nm = fmaxf(pm[nt], om);
            pz[nt] = pz[nt] * __expf(pm[nt] - nm) + oz * __expf(om - nm);
            pm[nt] = nm;
        }
    }
    __syncthreads();
    if (quad == 0) {
        #pragma unroll
        for (int nt = 0; nt < 2; nt++) {
            red2[wave * 32 + nt * 16 + m]       = pm[nt];
            red2[128 + wave * 32 + nt * 16 + m] = pz[nt];
        }
    }
    __syncthreads();
    if (t < 32) {
        float mf = -1e30f;
        #pragma unroll
        for (int w = 0; w < 4; w++) mf = fmaxf(mf, red2[w * 32 + t]);
        float z = 0.f;
        #pragma unroll
        for (int w = 0; w < 4; w++) z += red2[128 + w * 32 + t] * __expf(red2[w * 32 + t] - mf);
        ws[WS_PM + t * 800 + blockIdx.x] = mf;
        ws[WS_PZ + t * 800 + blockIdx.x] = z;
    }
}

// ---------------------------------------------------------------- log-softmax finalize:
// block = (1024-logit tile, b).  Combines the 786 per-tile partials in-block
// (6.3 KB, L2-hot, identical across blocks of same b), then subtracts.
__global__ __launch_bounds__(256) void k_lsm_final(const float* __restrict__ ws,
                                                   float* __restrict__ out) {
    int b = blockIdx.y, t = threadIdx.x;
    __shared__ float rm[256], rz[256];
    float m = -1e30f, z = 0.f;
    for (int i = t; i < NT_LOG; i += 256) {
        float mi = ws[WS_PM + b * 800 + i];
        float zi = ws[WS_PZ + b * 800 + i];
        float nm = fmaxf(m, mi);
        z = z * __expf(m - nm) + zi * __expf(mi - nm);
        m = nm;
    }
    rm[t] = m; rz[t] = z; __syncthreads();
    for (int off = 128; off; off >>= 1) {
        if (t < off) {
            float m2 = rm[t + off], z2 = rz[t + off];
            float nm = fmaxf(rm[t], m2);
            rz[t] = rz[t] * __expf(rm[t] - nm) + z2 * __expf(m2 - nm);
            rm[t] = nm;
        }
        __syncthreads();
    }
    float M = rm[0], LZ = logf(rz[0]);
    int rbase = blockIdx.x * 1024 + t;
    #pragma unroll
    for (int j = 0; j < 4; j++) {
        int r = rbase + 256 * j;
        if (r < V) {
            size_t i = (size_t)b * V + r;
            out[i] = out[i] - M - LZ;
        }
    }
}

extern "C" void kernel_launch(void* const* d_in, const int* in_sizes, int n_in,
                              void* d_out, int out_size, void* d_ws, size_t ws_size,
                              hipStream_t stream) {
    const int*   tokens = (const int*)d_in[0];
    const float* hidden = (const float*)d_in[1];
    const float* cell   = (const float*)d_in[2];
    const float* enc    = (const float*)d_in[3];
    const float* emb    = (const float*)d_in[4];
    const float* W_attn = (const float*)d_in[5];
    const float* v      = (const float*)d_in[7];
    const float* W_ih   = (const float*)d_in[8];
    const float* b_ih   = (const float*)d_in[9];
    const float* W_hh   = (const float*)d_in[10];
    const float* b_hh   = (const float*)d_in[11];
    const float* W_out  = (const float*)d_in[12];
    const float* b_out  = (const float*)d_in[13];
    float* out = (float*)d_out;
    float* ws  = (float*)d_ws;

    k_attn<<<B * NCH, 256, 0, stream>>>(W_attn, v, enc, ws);
    k_fuse<<<B * 16, 256, 0, stream>>>(tokens, emb, hidden, cell, W_ih, b_ih, W_hh, b_hh, ws, out);
    k_logits<<<NT_LOG, 256, 0, stream>>>(W_out, b_out, ws, out);
    k_lsm_final<<<dim3((V + 1023) / 1024, B), 256, 0, stream>>>(ws, out);
}

// Round 4
// 294.736 us; speedup vs baseline: 1.6621x; 1.0279x over previous
//
#include <hip/hip_runtime.h>
#include <cstddef>

#define H   256
#define L   2048
#define B   32
#define V   50257
#define H2  512
#define H4  1024
#define CH  64                        // flash chunk rows
#define NCH (L/CH)                    // 32 chunks per batch

// output flat offsets (floats)
#define LP_OFF 0
#define HN_OFF (B*V)                 // 1608224
#define CN_OFF (HN_OFF + B*H)        // 1616416
#define AW_OFF (CN_OFF + B*H)        // 1624608

// workspace layout (floats)
#define WS_WP    0                    // 32*256 w partials (k-sliced)
#define WS_XG    (WS_WP + 32*256)     // 32*512: [embedded | attn_applied]
#define WS_XL    (WS_XG + B*H2)       // 32*512: [h_new | attn_applied]
#define WS_S     (WS_XL + B*H2)       // 32*2048 raw scores
#define WS_AV    (WS_S + B*L)         // 1024*256 chunk partial vectors
#define WS_AM    (WS_AV + B*NCH*H)    // 1024 chunk max
#define WS_AZ    (WS_AM + B*NCH)      // 1024 chunk sumexp
#define WS_GATES (WS_AZ + B*NCH)      // 32*1024
#define WS_PM    (WS_GATES + B*H4)    // 32*800 lsm per-tile max
#define WS_PZ    (WS_PM + 32*800)     // 32*800 lsm per-tile sumexp
#define WS_M     (WS_PZ + 32*800)     // 32
#define WS_LZ    (WS_M + 32)          // 32

#define NBLK_LOG 786                  // ceil(V/64) 64-row logit tiles

typedef __attribute__((ext_vector_type(8))) short bf16x8;
typedef __attribute__((ext_vector_type(4))) float f32x4;

__device__ inline unsigned short f2bf(float f) {
    unsigned u = __builtin_bit_cast(unsigned, f);
    u += 0x7FFFu + ((u >> 16) & 1u);          // RNE to bf16
    return (unsigned short)(u >> 16);
}

// ---------------------------------------------------------------- prep (distributed):
// block p (of 32) handles k-slice [8p, 8p+8): partial[h] = sum v[k]*W_attn[k, H+h]
__global__ __launch_bounds__(256) void k_prep(const float* __restrict__ W_attn,
                                              const float* __restrict__ v,
                                              float* __restrict__ ws) {
    int p = blockIdx.x, t = threadIdx.x;
    const float* base = W_attn + H + t;
    float acc = 0.f;
    #pragma unroll
    for (int kk = 0; kk < 8; kk++) {
        int k = p * 8 + kk;
        acc += v[k] * base[(size_t)k * H2];
    }
    ws[WS_WP + p * 256 + t] = acc;
}

// ---------------------------------------------------------------- flash attention (one enc pass):
// block = (b, chunk of 64 l).  Reduces w partials (L2-hot), then scores with
// k-split-16 (4 rows/wave in parallel, 4 shuffle steps), chunk softmax partial,
// weighted vector partial from L1/L2-hot enc rows.
__global__ __launch_bounds__(256) void k_attn_flash(const float* __restrict__ enc,
                                                    float* __restrict__ ws) {
    int bid = blockIdx.x;             // b*NCH + chunk
    int b = bid >> 5, chunk = bid & (NCH - 1);
    int t = threadIdx.x;
    int wave = t >> 6, lane = t & 63;
    int g = lane >> 4, u = lane & 15;
    __shared__ float w_s[256];
    __shared__ float s_lds[CH];
    __shared__ float p_lds[CH];
    __shared__ float red[CH];
    __shared__ float vec_lds[4][256];

    // combine w partials (same 32 KB for every block -> L2-resident)
    float wsum = 0.f;
    #pragma unroll 8
    for (int p = 0; p < 32; p++) wsum += ws[WS_WP + p * 256 + t];
    w_s[t] = wsum;
    __syncthreads();

    size_t rowbase = (size_t)b * L + chunk * CH;
    const float4* w4s = (const float4*)w_s;
    float4 w0 = w4s[u], w1 = w4s[16 + u], w2 = w4s[32 + u], w3 = w4s[48 + u];

    // phase 1: scores.  wave handles rows [wave*16, wave*16+16), 4 at a time (one per g);
    // 16 lanes (u) split k, 4 independent float4 loads per lane per row.
    #pragma unroll
    for (int ir = 0; ir < 4; ir++) {
        int rl = wave * 16 + ir * 4 + g;
        const float4* e4 = (const float4*)(enc + (rowbase + rl) * H);
        float4 a0 = e4[u], a1 = e4[16 + u], a2 = e4[32 + u], a3 = e4[48 + u];
        float p = a0.x * w0.x + a0.y * w0.y + a0.z * w0.z + a0.w * w0.w
                + a1.x * w1.x + a1.y * w1.y + a1.z * w1.z + a1.w * w1.w
                + a2.x * w2.x + a2.y * w2.y + a2.z * w2.z + a2.w * w2.w
                + a3.x * w3.x + a3.y * w3.y + a3.z * w3.z + a3.w * w3.w;
        p += __shfl_down(p, 8); p += __shfl_down(p, 4);
        p += __shfl_down(p, 2); p += __shfl_down(p, 1);
        if (u == 0) s_lds[rl] = p;
    }
    __syncthreads();

    // chunk softmax partial over 64 rows
    if (t < CH) red[t] = s_lds[t];
    __syncthreads();
    for (int off = 32; off; off >>= 1) { if (t < off) red[t] = fmaxf(red[t], red[t + off]); __syncthreads(); }
    float m = red[0];
    __syncthreads();
    if (t < CH) {
        float e = __expf(s_lds[t] - m);
        p_lds[t] = e; red[t] = e;
        ws[WS_S + rowbase + t] = s_lds[t];
    }
    __syncthreads();
    for (int off = 32; off; off >>= 1) { if (t < off) red[t] += red[t + off]; __syncthreads(); }

    // phase 2: weighted vector partial; wave w covers rows [w*16, w*16+16), lane = h float4
    float4 acc = make_float4(0.f, 0.f, 0.f, 0.f);
    const float4* ebase = (const float4*)(enc + (rowbase + wave * 16) * H);
    #pragma unroll 4
    for (int i = 0; i < 16; i++) {
        float p = p_lds[wave * 16 + i];
        float4 a = ebase[i * 64 + lane];
        acc.x += p * a.x; acc.y += p * a.y; acc.z += p * a.z; acc.w += p * a.w;
    }
    *(float4*)&vec_lds[wave][lane * 4] = acc;
    __syncthreads();
    ws[WS_AV + (size_t)bid * 256 + t] = vec_lds[0][t] + vec_lds[1][t] + vec_lds[2][t] + vec_lds[3][t];
    if (t == 0) { ws[WS_AM + bid] = m; ws[WS_AZ + bid] = red[0]; }
}

// ---------------------------------------------------------------- combine chunk partials per b:
// attn_applied = (1/Z) sum_c e^{m_c-M} vec_c;  write attn_weights output; embed gather.
__global__ __launch_bounds__(256) void k_attn_comb(const int* __restrict__ tokens,
                                                   const float* __restrict__ emb,
                                                   float* __restrict__ ws,
                                                   float* __restrict__ out) {
    int b = blockIdx.x, t = threadIdx.x;
    __shared__ float mc[NCH], zc[NCH];
    if (t < NCH) { mc[t] = ws[WS_AM + b * NCH + t]; zc[t] = ws[WS_AZ + b * NCH + t]; }
    __syncthreads();
    float M = -1e30f;
    #pragma unroll
    for (int c = 0; c < NCH; c++) M = fmaxf(M, mc[c]);
    float Z = 0.f;
    #pragma unroll
    for (int c = 0; c < NCH; c++) Z += zc[c] * __expf(mc[c] - M);
    float inv = 1.f / Z;
    float acc = 0.f;
    #pragma unroll 8
    for (int c = 0; c < NCH; c++) acc += __expf(mc[c] - M) * ws[WS_AV + (size_t)(b * NCH + c) * 256 + t];
    acc *= inv;
    ws[WS_XG + b * H2 + H + t] = acc;
    ws[WS_XL + b * H2 + H + t] = acc;
    int tok = tokens[b];
    ws[WS_XG + b * H2 + t] = emb[(size_t)tok * H + t];
    #pragma unroll
    for (int j = 0; j < 8; j++) {
        int l = t + 256 * j;
        out[AW_OFF + (size_t)b * L + l] = __expf(ws[WS_S + (size_t)b * L + l] - M) * inv;
    }
}

// ---------------------------------------------------------------- LSTM gates:
// one wave per (b, j): gates = x @ W_ih^T + b_ih + h @ W_hh^T + b_hh
__global__ __launch_bounds__(256) void k_gates(const float* __restrict__ W_ih, const float* __restrict__ b_ih,
                                               const float* __restrict__ W_hh, const float* __restrict__ b_hh,
                                               const float* __restrict__ hidden, float* __restrict__ ws) {
    int t = threadIdx.x;
    int wave = t >> 6, lane = t & 63;
    int o = blockIdx.x * 4 + wave;        // b*1024 + j
    int b = o >> 10, j = o & 1023;
    const float4* wi = (const float4*)(W_ih + (size_t)j * H2);
    const float4* xg = (const float4*)(ws + WS_XG + (size_t)b * H2);
    float4 a0 = wi[lane * 2], a1 = wi[lane * 2 + 1];
    float4 x0 = xg[lane * 2], x1 = xg[lane * 2 + 1];
    float p = a0.x * x0.x + a0.y * x0.y + a0.z * x0.z + a0.w * x0.w
            + a1.x * x1.x + a1.y * x1.y + a1.z * x1.z + a1.w * x1.w;
    const float4* wh = (const float4*)(W_hh + (size_t)j * H);
    const float4* hp = (const float4*)(hidden + (size_t)b * H);
    float4 a2 = wh[lane], x2 = hp[lane];
    p += a2.x * x2.x + a2.y * x2.y + a2.z * x2.z + a2.w * x2.w;
    #pragma unroll
    for (int off = 32; off; off >>= 1) p += __shfl_down(p, off);
    if (lane == 0) ws[WS_GATES + o] = p + b_ih[j] + b_hh[j];
}

// ---------------------------------------------------------------- LSTM cell pointwise
__global__ __launch_bounds__(256) void k_lstm(const float* __restrict__ cell,
                                              float* __restrict__ ws, float* __restrict__ out) {
    int b = blockIdx.x, t = threadIdx.x;
    const float* g = ws + WS_GATES + (size_t)b * H4;
    float ig = g[t], fg = g[H + t], gg = g[2 * H + t], og = g[3 * H + t];
    float c = cell[(size_t)b * H + t];
    float si = 1.f / (1.f + expf(-ig));
    float sf = 1.f / (1.f + expf(-fg));
    float so = 1.f / (1.f + expf(-og));
    float cn = sf * c + si * tanhf(gg);
    float hn = so * tanhf(cn);
    out[HN_OFF + b * H + t] = hn;
    out[CN_OFF + b * H + t] = cn;
    ws[WS_XL + b * H2 + t] = hn;
}

// ---------------------------------------------------------------- logits (bf16 MFMA):
// 786 blocks x 64 rows.  wave = one 16-row strip x 32 batches (2 n-tiles).
// Depth-3 rotating register prefetch of W_out (6 x float4 in flight per lane);
// no min-wave launch bound (VGPR free, no spills).
__global__ __launch_bounds__(256) void k_logits(const float* __restrict__ W_out,
                                                const float* __restrict__ b_out,
                                                float* __restrict__ ws,
                                                float* __restrict__ out) {
    __shared__ unsigned short Xl[32 * 520];   // 33,280 B
    __shared__ float red2[256];
    int t = threadIdx.x;
    const float4* xl4 = (const float4*)(ws + WS_XL);
    #pragma unroll
    for (int it = 0; it < 16; it++) {
        int fi = t + 256 * it;                // float4 index over 32x128
        int bb = fi >> 7, kq = fi & 127;
        float4 xv = xl4[bb * 128 + kq];
        unsigned p0 = (unsigned)f2bf(xv.x) | ((unsigned)f2bf(xv.y) << 16);
        unsigned p1 = (unsigned)f2bf(xv.z) | ((unsigned)f2bf(xv.w) << 16);
        unsigned* dst = (unsigned*)&Xl[bb * 520 + kq * 4];
        dst[0] = p0; dst[1] = p1;
    }
    __syncthreads();

    int wave = t >> 6, lane = t & 63, quad = lane >> 4, m = lane & 15;
    int rbase = blockIdx.x * 64 + wave * 16;
    int r0 = rbase + m;
    int rc = r0 < V ? r0 : V - 1;
    const float4* wq = (const float4*)(W_out + (size_t)rc * H2 + quad * 8);

    f32x4 acc0 = {0.f, 0.f, 0.f, 0.f}, acc1 = {0.f, 0.f, 0.f, 0.f};

    // depth-3 prefetch ring (kp, kp+1, kp+2 resident; kp+3 issued on rotate)
    float4 pl0 = wq[0],  ph0 = wq[1];
    float4 pl1 = wq[8],  ph1 = wq[9];
    float4 pl2 = wq[16], ph2 = wq[17];
    #pragma unroll
    for (int kp = 0; kp < 16; kp++) {
        int k0 = kp * 32;
        bf16x8 a;
        a[0]=(short)f2bf(pl0.x); a[1]=(short)f2bf(pl0.y); a[2]=(short)f2bf(pl0.z); a[3]=(short)f2bf(pl0.w);
        a[4]=(short)f2bf(ph0.x); a[5]=(short)f2bf(ph0.y); a[6]=(short)f2bf(ph0.z); a[7]=(short)f2bf(ph0.w);
        bf16x8 b0 = *(bf16x8*)&Xl[(size_t)m * 520 + k0 + quad * 8];
        bf16x8 b1 = *(bf16x8*)&Xl[(size_t)(16 + m) * 520 + k0 + quad * 8];
        acc0 = __builtin_amdgcn_mfma_f32_16x16x32_bf16(a, b0, acc0, 0, 0, 0);
        acc1 = __builtin_amdgcn_mfma_f32_16x16x32_bf16(a, b1, acc1, 0, 0, 0);
        pl0 = pl1; ph0 = ph1;
        pl1 = pl2; ph1 = ph2;
        if (kp < 13) { pl2 = wq[(kp + 3) * 8]; ph2 = wq[(kp + 3) * 8 + 1]; }
    }

    // epilogue: bias, store, per-wave softmax partials
    float val[2][4];
    #pragma unroll
    for (int i = 0; i < 4; i++) {
        int rr = rbase + quad * 4 + i;
        float bo = (rr < V) ? b_out[rr] : 0.f;
        float v0 = acc0[i] + bo, v1 = acc1[i] + bo;
        if (rr < V) {
            out[(size_t)m * V + rr]        = v0;
            out[(size_t)(16 + m) * V + rr] = v1;
            val[0][i] = v0; val[1][i] = v1;
        } else { val[0][i] = -1e30f; val[1][i] = -1e30f; }
    }
    float pm[2], pz[2];
    #pragma unroll
    for (int nt = 0; nt < 2; nt++) {
        float mx = -1e30f;
        #pragma unroll
        for (int i = 0; i < 4; i++) mx = fmaxf(mx, val[nt][i]);
        float sm = 0.f;
        #pragma unroll
        for (int i = 0; i < 4; i++) sm += __expf(val[nt][i] - mx);
        pm[nt] = mx; pz[nt] = sm;
    }
    #pragma unroll
    for (int off = 16; off <= 32; off <<= 1) {
        #pragma unroll
        for (int nt = 0; nt < 2; nt++) {
            float om = __shfl_xor(pm[nt], off);
            float oz = __shfl_xor(pz[nt], off);
            float nm = fmaxf(pm[nt], om);
            pz[nt] = pz[nt] * __expf(pm[nt] - nm) + oz * __expf(om - nm);
            pm[nt] = nm;
        }
    }
    __syncthreads();
    if (quad == 0) {
        #pragma unroll
        for (int nt = 0; nt < 2; nt++) {
            red2[wave * 32 + nt * 16 + m]       = pm[nt];
            red2[128 + wave * 32 + nt * 16 + m] = pz[nt];
        }
    }
    __syncthreads();
    if (t < 32) {
        float mf = -1e30f;
        #pragma unroll
        for (int w = 0; w < 4; w++) mf = fmaxf(mf, red2[w * 32 + t]);
        float z = 0.f;
        #pragma unroll
        for (int w = 0; w < 4; w++) z += red2[128 + w * 32 + t] * __expf(red2[w * 32 + t] - mf);
        ws[WS_PM + t * 800 + blockIdx.x] = mf;
        ws[WS_PZ + t * 800 + blockIdx.x] = z;
    }
}

// ---------------------------------------------------------------- combine log-softmax partials
__global__ __launch_bounds__(256) void k_lsm_comb(float* __restrict__ ws) {
    int b = blockIdx.x, t = threadIdx.x;
    float m = -1e30f, z = 0.f;
    for (int i = t; i < NBLK_LOG; i += 256) {
        float mi = ws[WS_PM + b * 800 + i];
        float zi = ws[WS_PZ + b * 800 + i];
        float nm = fmaxf(m, mi);
        z = z * __expf(m - nm) + zi * __expf(mi - nm);
        m = nm;
    }
    __shared__ float rm[256], rz[256];
    rm[t] = m; rz[t] = z; __syncthreads();
    for (int off = 128; off; off >>= 1) {
        if (t < off) {
            float m2 = rm[t + off], z2 = rz[t + off];
            float nm = fmaxf(rm[t], m2);
            rz[t] = rz[t] * __expf(rm[t] - nm) + z2 * __expf(m2 - nm);
            rm[t] = nm;
        }
        __syncthreads();
    }
    if (t == 0) { ws[WS_M + b] = rm[0]; ws[WS_LZ + b] = logf(rz[0]); }
}

__global__ __launch_bounds__(256) void k_lsm_final(const float* __restrict__ ws, float* __restrict__ out) {
    int b = blockIdx.y;
    int r = blockIdx.x * 256 + threadIdx.x;
    if (r < V) {
        size_t i = (size_t)b * V + r;
        out[i] = out[i] - ws[WS_M + b] - ws[WS_LZ + b];
    }
}

extern "C" void kernel_launch(void* const* d_in, const int* in_sizes, int n_in,
                              void* d_out, int out_size, void* d_ws, size_t ws_size,
                              hipStream_t stream) {
    const int*   tokens = (const int*)d_in[0];
    const float* hidden = (const float*)d_in[1];
    const float* cell   = (const float*)d_in[2];
    const float* enc    = (const float*)d_in[3];
    const float* emb    = (const float*)d_in[4];
    const float* W_attn = (const float*)d_in[5];
    const float* v      = (const float*)d_in[7];
    const float* W_ih   = (const float*)d_in[8];
    const float* b_ih   = (const float*)d_in[9];
    const float* W_hh   = (const float*)d_in[10];
    const float* b_hh   = (const float*)d_in[11];
    const float* W_out  = (const float*)d_in[12];
    const float* b_out  = (const float*)d_in[13];
    float* out = (float*)d_out;
    float* ws  = (float*)d_ws;

    k_prep<<<32, 256, 0, stream>>>(W_attn, v, ws);
    k_attn_flash<<<B * NCH, 256, 0, stream>>>(enc, ws);
    k_attn_comb<<<B, 256, 0, stream>>>(tokens, emb, ws, out);
    k_gates<<<(B * H4) / 4, 256, 0, stream>>>(W_ih, b_ih, W_hh, b_hh, hidden, ws);
    k_lstm<<<B, 256, 0, stream>>>(cell, ws, out);
    k_logits<<<NBLK_LOG, 256, 0, stream>>>(W_out, b_out, ws, out);
    k_lsm_comb<<<B, 256, 0, stream>>>(ws);
    k_lsm_final<<<dim3((V + 255) / 256, B), 256, 0, stream>>>(ws, out);
}